// Round 2
// baseline (422.312 us; speedup 1.0000x reference)
//
#include <hip/hip_runtime.h>
#include <cstdint>
#include <cstddef>

// Problem: a[B=4,S=2048,K=4096] int8, w[K=4096,N=4096] int8,
// a_s[8192] f32 per-token scale, w_s[4096] f32 per-col scale.
// out[m][n] = fp16( (int32 dot) * a_s[m] * w_s[n] ), stored as f32 in d_out.
//
// HARNESS NOTE: integer inputs arrive as *int32* buffers (one int32 per
// reference int8 element). A fused pre-pass narrows them to packed int8 in
// d_ws (A: same layout; W: transposed to [N][K]) before the MFMA GEMM.

#define M_DIM 8192
#define N_DIM 4096
#define K_DIM 4096

// pack-A portion: one thread per 4 int32 -> 1 uint32. M*K/4 = 8M threads.
#define PACKA_BLOCKS ((M_DIM * K_DIM / 4) / 256)   // 32768
// transpose portion: 64x64 tiles -> (4096/64)*(4096/64) = 4096 blocks.
#define TRANS_BLOCKS ((N_DIM / 64) * (K_DIM / 64)) // 4096

typedef int v4i  __attribute__((ext_vector_type(4)));
typedef int v16i __attribute__((ext_vector_type(16)));

__device__ __forceinline__ uint32_t pack4(int x, int y, int z, int w)
{
    return (uint32_t)(x & 0xff) | ((uint32_t)(y & 0xff) << 8) |
           ((uint32_t)(z & 0xff) << 16) | ((uint32_t)(w & 0xff) << 24);
}

// ---------------------------------------------------------------------------
// Fused pre-pass: blocks [0, PACKA_BLOCKS) narrow A (layout-preserving,
// fully coalesced). Blocks [PACKA_BLOCKS, ...) narrow + transpose W via
// 64x64 LDS tiles.
// ---------------------------------------------------------------------------
__global__ void __launch_bounds__(256) prepare_kernel(
    const int* __restrict__ a, const int* __restrict__ w,
    uint8_t* __restrict__ pa, uint8_t* __restrict__ wt)
{
    __shared__ int lds[64][65];        // used by transpose branch only

    if (blockIdx.x < PACKA_BLOCKS) {
        const size_t idx = (size_t)blockIdx.x * 256 + threadIdx.x;
        int4 x = ((const int4*)a)[idx];
        ((uint32_t*)pa)[idx] = pack4(x.x, x.y, x.z, x.w);
        return;
    }

    const int tile = blockIdx.x - PACKA_BLOCKS;
    const int t  = threadIdx.x;
    const int n0 = (tile & 63) * 64;
    const int k0 = (tile >> 6) * 64;

#pragma unroll
    for (int i = 0; i < 4; ++i) {
        int v   = t + 256 * i;         // 0..1023 int4-groups
        int row = v >> 4;              // k within tile
        int cq  = v & 15;              // int4 group within row
        int4 x = *(const int4*)(w + (size_t)(k0 + row) * N_DIM + n0 + cq * 4);
        lds[row][cq * 4 + 0] = x.x;
        lds[row][cq * 4 + 1] = x.y;
        lds[row][cq * 4 + 2] = x.z;
        lds[row][cq * 4 + 3] = x.w;
    }
    __syncthreads();

    const int n_local = t >> 2;        // 0..63
    const int c       = t & 3;         // 16-byte k-chunk
    uint32_t o[4];
#pragma unroll
    for (int j = 0; j < 4; ++j)
        o[j] = pack4(lds[c * 16 + j * 4 + 0][n_local],
                     lds[c * 16 + j * 4 + 1][n_local],
                     lds[c * 16 + j * 4 + 2][n_local],
                     lds[c * 16 + j * 4 + 3][n_local]);
    *(uint4*)(wt + (size_t)(n0 + n_local) * K_DIM + k0 + c * 16) =
        make_uint4(o[0], o[1], o[2], o[3]);
}

// ---------------------------------------------------------------------------
// int8 GEMM — 256x256 tile, 8 waves (512 thr), BK=128 bytes, double-buffered
// LDS (128 KiB), phase-split K-tile (4 k-steps of 32) with counted
// s_waitcnt vmcnt(4) + raw s_barrier (T3+T4) and s_setprio around the MFMA
// clusters (T5).  Each wave computes 128x64 via 4x2 grid of
// mfma_i32_32x32x32_i8, 0.75 ds_read_b128 per MFMA.
//
// LDS layout: s?[dbuf][khalf][256 rows][64 bytes], 16B-chunk swizzle
// chunk' = chunk ^ ((row>>1)&3) applied on BOTH the (pre-swizzled) global
// source address at staging time and the ds_read address — keeps the
// global_load_lds destination linear while giving each 32-lane half an even
// 8-bank-group x 4-lane distribution on ds_read_b128.
//
// Staging order per K-tile t (issued for t+1 while computing t):
//   phase0: A-klo   phase1: B-klo   [vmcnt(4) barrier]
//   phase2: A-khi   phase3: B-khi   [vmcnt(4) barrier]
// so each vmcnt(4) retires exactly the k-half consumed next; loads for the
// other half stay in flight across the barrier (never drained to 0 in-loop).
// ---------------------------------------------------------------------------
__device__ __forceinline__ void async_copy16(const void* gptr, void* lptr)
{
    __builtin_amdgcn_global_load_lds(
        (const __attribute__((address_space(1))) uint32_t*)gptr,
        (__attribute__((address_space(3))) uint32_t*)lptr,
        16, 0, 0);
}

#define VMCNT4() asm volatile("s_waitcnt vmcnt(4)" ::: "memory")
#define VMCNT0() asm volatile("s_waitcnt vmcnt(0)" ::: "memory")

__global__ void __launch_bounds__(512, 2) int8_gemm_kernel(
    const uint8_t* __restrict__ A,    // [M][K] int8 bytes (packed)
    const uint8_t* __restrict__ Wt,   // [N][K] int8 bytes (pre-transposed)
    const float*   __restrict__ a_s,  // [M]
    const float*   __restrict__ w_s,  // [N]
    float*         __restrict__ out)  // [M][N] f32 (fp16-rounded)
{
    // [dbuf][khalf][256*64]
    __shared__ __align__(16) uint8_t sA[2][2][256 * 64];
    __shared__ __align__(16) uint8_t sB[2][2][256 * 64];

    const int tid   = threadIdx.x;
    const int wave  = tid >> 6;       // 0..7
    const int lane  = tid & 63;
    const int waveM = wave >> 2;      // 0..1  -> 128-row M slab
    const int waveN = wave & 3;       // 0..3  -> 64-col N slab

    const int bm = blockIdx.x & 31;   // 32 m-blocks (fast: share B panel)
    const int bn = blockIdx.x >> 5;   // 16 n-blocks
    const int m0 = bm * 256;
    const int n0 = bn * 256;

    v16i acc[4][2];
#pragma unroll
    for (int i = 0; i < 4; ++i)
#pragma unroll
        for (int j = 0; j < 2; ++j)
#pragma unroll
            for (int r = 0; r < 16; ++r)
                acc[i][j][r] = 0;

    // ---- staging: one k-half (256 rows x 64 B = 16 KB) per call;
    // 2 global_load_lds per thread, each wave fills 2x 1 KiB linear regions.
    auto stageA = [&](int buf, int kh, int kt) {
#pragma unroll
        for (int l = 0; l < 2; ++l) {
            const int region = l * 8 + wave;          // wave-uniform
            const int i      = region * 64 + lane;    // 16B-chunk index 0..1023
            const int row    = i >> 2;                // 0..255
            const int g      = (i & 3) ^ ((row >> 1) & 3);   // pre-swizzled src
            async_copy16(A + (size_t)(m0 + row) * K_DIM + kt * 128 + kh * 64 + g * 16,
                         &sA[buf][kh][region * 1024]);
        }
    };
    auto stageB = [&](int buf, int kh, int kt) {
#pragma unroll
        for (int l = 0; l < 2; ++l) {
            const int region = l * 8 + wave;
            const int i      = region * 64 + lane;
            const int row    = i >> 2;
            const int g      = (i & 3) ^ ((row >> 1) & 3);
            async_copy16(Wt + (size_t)(n0 + row) * K_DIM + kt * 128 + kh * 64 + g * 16,
                         &sB[buf][kh][region * 1024]);
        }
    };

    // Fragment geometry for 32x32x32 i8:
    //   A: lane holds A[m = lane&31][k = (lane>>5)*16 .. +15]
    //   B: lane holds B[k = (lane>>5)*16 .. +15][n = lane&31]  (Wt row-major)
    const int frow = lane & 31;
    const int fk   = lane >> 5;

    // one k-step (32 bytes of K): 4 A-frags + 2 B-frags -> 8 MFMAs
    auto compute_kstep = [&](int buf, int s) {
        const int kh = s >> 1;
        const int c  = (s & 1) * 2 + fk;              // chunk within k-half
        v4i af[4], bf[2];
#pragma unroll
        for (int mt = 0; mt < 4; ++mt) {
            const int ra = waveM * 128 + mt * 32 + frow;
            af[mt] = *(const v4i*)(&sA[buf][kh][ra * 64 + ((c ^ ((ra >> 1) & 3)) << 4)]);
        }
#pragma unroll
        for (int nt = 0; nt < 2; ++nt) {
            const int rb = waveN * 64 + nt * 32 + frow;
            bf[nt] = *(const v4i*)(&sB[buf][kh][rb * 64 + ((c ^ ((rb >> 1) & 3)) << 4)]);
        }
        __builtin_amdgcn_s_setprio(1);
#pragma unroll
        for (int mt = 0; mt < 4; ++mt)
#pragma unroll
            for (int nt = 0; nt < 2; ++nt)
                acc[mt][nt] = __builtin_amdgcn_mfma_i32_32x32x32_i8(
                    af[mt], bf[nt], acc[mt][nt], 0, 0, 0);
        __builtin_amdgcn_s_setprio(0);
    };

    const int NT = K_DIM / 128;       // 32 K-tiles

    // ---- prologue: stage tile 0 (A-klo, B-klo, A-khi, B-khi), retire klo.
    stageA(0, 0, 0);
    stageB(0, 0, 0);
    stageA(0, 1, 0);
    stageB(0, 1, 0);
    VMCNT4();                          // A-klo(0)+B-klo(0) landed
    __builtin_amdgcn_s_barrier();

    // ---- main loop: compute tile kt, stage tile kt+1.
    for (int kt = 0; kt < NT - 1; ++kt) {
        const int b = kt & 1;
        // phases 0,1: k-steps 0,1 (k-lo of tile kt) ; stage k-lo of kt+1
        stageA(b ^ 1, 0, kt + 1);
        compute_kstep(b, 0);
        stageB(b ^ 1, 0, kt + 1);
        compute_kstep(b, 1);
        VMCNT4();                      // retires A-khi(kt)+B-khi(kt)
        __builtin_amdgcn_s_barrier();
        // phases 2,3: k-steps 2,3 (k-hi of tile kt) ; stage k-hi of kt+1
        stageA(b ^ 1, 1, kt + 1);
        compute_kstep(b, 2);
        stageB(b ^ 1, 1, kt + 1);
        compute_kstep(b, 3);
        VMCNT4();                      // retires A-klo(kt+1)+B-klo(kt+1)
        __builtin_amdgcn_s_barrier();
    }
    // ---- last tile: no staging.
    {
        const int b = (NT - 1) & 1;
        compute_kstep(b, 0);
        compute_kstep(b, 1);
        VMCNT0();                      // retires A-khi+B-khi of last tile
        __builtin_amdgcn_s_barrier();
        compute_kstep(b, 2);
        compute_kstep(b, 3);
    }

    // ---- epilogue. 32x32 C/D layout: col = lane&31,
    // row = (reg&3) + 8*(reg>>2) + 4*(lane>>5).
    const int col   = lane & 31;
    const int rbase = (lane >> 5) * 4;

#pragma unroll
    for (int mt = 0; mt < 4; ++mt) {
        const int mrow0 = m0 + waveM * 128 + mt * 32 + rbase;
        float asv[16];
#pragma unroll
        for (int reg = 0; reg < 16; ++reg)
            asv[reg] = a_s[mrow0 + (reg & 3) + 8 * (reg >> 2)];
#pragma unroll
        for (int nt = 0; nt < 2; ++nt) {
            const int n = n0 + waveN * 64 + nt * 32 + col;
            const float wsv = w_s[n];
#pragma unroll
            for (int reg = 0; reg < 16; ++reg) {
                const int row = mrow0 + (reg & 3) + 8 * (reg >> 2);
                float v = (float)acc[mt][nt][reg] * asv[reg] * wsv;
                v = (float)(_Float16)v;   // match reference's fp16 cast
                out[(size_t)row * N_DIM + n] = v;
            }
        }
    }
}

// ---------------------------------------------------------------------------
extern "C" void kernel_launch(void* const* d_in, const int* in_sizes, int n_in,
                              void* d_out, int out_size, void* d_ws, size_t ws_size,
                              hipStream_t stream)
{
    const int*   a   = (const int*)  d_in[0];  // int32-widened int8 [8192][4096]
    const float* a_s = (const float*)d_in[1];  // [8192]
    const int*   w   = (const int*)  d_in[2];  // int32-widened int8 [4096][4096]
    const float* w_s = (const float*)d_in[3];  // [4096]
    float*       out = (float*)d_out;

    uint8_t* wt = (uint8_t*)d_ws;                          // 16 MiB
    uint8_t* pa = (uint8_t*)d_ws + (size_t)N_DIM * K_DIM;  // 32 MiB

    prepare_kernel<<<PACKA_BLOCKS + TRANS_BLOCKS, 256, 0, stream>>>(a, w, pa, wt);

    int8_gemm_kernel<<<(M_DIM / 256) * (N_DIM / 256), 512, 0, stream>>>(
        pa, wt, a_s, w_s, out);
}